// Round 1
// 205.569 us; speedup vs baseline: 1.0995x; 1.0995x over previous
//
#include <hip/hip_runtime.h>

#define NB 32
#define CCH 128
#define HH 56
#define WWD 56
#define HWP (HH*WWD)   // 3136
#define K3C (3*CCH)    // 384
#define SPLITK 8

typedef _Float16 half8 __attribute__((ext_vector_type(8)));
typedef float floatx4 __attribute__((ext_vector_type(4)));

// ---------------- prep: p2w f32 -> f16, K-permuted: row k' = j*128+c <- src row (c,j) ----------
__global__ __launch_bounds__(256) void cvtp2w_kernel(const float* __restrict__ src,
                                                     _Float16* __restrict__ dst) {
    const int row = blockIdx.x;          // k' = j*128 + c
    const int j = row >> 7;
    const int c = row & 127;
    const float* s = src + ((size_t)c * 3 + j) * HWP;
    _Float16* d = dst + (size_t)row * HWP;
    for (int base = threadIdx.x * 8; base < HWP; base += 2048) {
        const float4 a = *(const float4*)(s + base);
        const float4 b = *(const float4*)(s + base + 4);
        half8 v;
        v[0] = (_Float16)a.x; v[1] = (_Float16)a.y; v[2] = (_Float16)a.z; v[3] = (_Float16)a.w;
        v[4] = (_Float16)b.x; v[5] = (_Float16)b.y; v[6] = (_Float16)b.z; v[7] = (_Float16)b.w;
        *(half8*)(d + base) = v;
    }
}

// ---------------- fused: x f32 -> xh f16 AND xT[n][p][c] transpose (64x64 LDS tiles) ----------
// grid 3136 = 8 * (4n * 2c * 49p); XCD swizzle n%8 == bid%8
__global__ __launch_bounds__(256) void cvt_xt_kernel(const float* __restrict__ x,
                                                     _Float16* __restrict__ xh,
                                                     _Float16* __restrict__ xT) {
    __shared__ _Float16 t[64 * 72];
    const int bid = blockIdx.x;
    const int r8  = bid & 7;
    const int g   = bid >> 3;            // 0..391
    const int n   = r8 + 8 * (g / 98);
    const int rem = g % 98;
    const int c0  = (rem / 49) * 64;
    const int p0  = (rem % 49) * 64;
    const int tid = threadIdx.x;
    const int r   = tid >> 2;            // 0..63
    const int seg = (tid & 3) * 16;

    const float* src = x + ((size_t)n * CCH + c0 + r) * HWP + p0 + seg;
    const float4 a0 = *(const float4*)(src);
    const float4 a1 = *(const float4*)(src + 4);
    const float4 a2 = *(const float4*)(src + 8);
    const float4 a3 = *(const float4*)(src + 12);
    half8 v0, v1;
    v0[0] = (_Float16)a0.x; v0[1] = (_Float16)a0.y; v0[2] = (_Float16)a0.z; v0[3] = (_Float16)a0.w;
    v0[4] = (_Float16)a1.x; v0[5] = (_Float16)a1.y; v0[6] = (_Float16)a1.z; v0[7] = (_Float16)a1.w;
    v1[0] = (_Float16)a2.x; v1[1] = (_Float16)a2.y; v1[2] = (_Float16)a2.z; v1[3] = (_Float16)a2.w;
    v1[4] = (_Float16)a3.x; v1[5] = (_Float16)a3.y; v1[6] = (_Float16)a3.z; v1[7] = (_Float16)a3.w;

    _Float16* dxh = xh + ((size_t)n * CCH + c0 + r) * HWP + p0 + seg;
    *(half8*)(dxh)     = v0;
    *(half8*)(dxh + 8) = v1;
    *(half8*)(&t[r * 72 + seg])     = v0;
    *(half8*)(&t[r * 72 + seg + 8]) = v1;
    __syncthreads();
    // write rows of xT: p_local = r, c chunk = seg..seg+15
    _Float16* dst = xT + ((size_t)n * HWP + p0 + r) * CCH + c0 + seg;
    half8 w0, w1;
#pragma unroll
    for (int i = 0; i < 8; ++i) w0[i] = t[(seg + i) * 72 + r];
#pragma unroll
    for (int i = 0; i < 8; ++i) w1[i] = t[(seg + 8 + i) * 72 + r];
    *(half8*)(dst) = w0;
    *(half8*)(dst + 8) = w1;
}

// ---------------- t8: t8[n,o,p] = sum_c conv_w[o,c]*p5w[c]*x[n,c,roll(p)] ----------------
__global__ __launch_bounds__(64) void t8_kernel(const _Float16* __restrict__ xh,
                                                const float* __restrict__ conv_w,
                                                const float* __restrict__ p5w,
                                                float* __restrict__ t8) {
    const int bid = blockIdx.x;
    const int r8  = bid & 7;
    const int g   = bid >> 3;
    const int n   = r8 + 8 * (g / 49);
    const int p   = (g % 49) * 64 + threadIdx.x;
    const int proll = (p >= WWD) ? (p - WWD) : (p + (HH - 1) * WWD);
    const _Float16* xb = xh + (size_t)n * CCH * HWP + proll;
    float a0 = 0.f, a1 = 0.f, a2 = 0.f, a3 = 0.f;
#pragma unroll 4
    for (int c = 0; c < CCH; ++c) {
        const float xp = (float)xb[(size_t)c * HWP] * p5w[c];
        a0 += conv_w[c] * xp;
        a1 += conv_w[CCH + c] * xp;
        a2 += conv_w[2 * CCH + c] * xp;
        a3 += conv_w[3 * CCH + c] * xp;
    }
    float* dst = t8 + (size_t)n * 4 * HWP + p;
    dst[0] = a0; dst[HWP] = a1; dst[2 * HWP] = a2; dst[3 * HWP] = a3;
}

// ---------------- GEMM1 (split-K, permuted K, f16 partials, reg-prefetch pipeline) ----------
// k' = j*128+c; m0-block has uniform j. Tm=128, Tn=128, BK=64; grid 768; swizzle n%8==bid%8.
__global__ __launch_bounds__(256) void gemm1_kernel(const _Float16* __restrict__ xh,
                                                    const _Float16* __restrict__ p2wh,
                                                    _Float16* __restrict__ part) {
    __shared__ _Float16 As[128 * 72];
    __shared__ _Float16 Bs[128 * 72];

    const int bid   = blockIdx.x;
    const int r8    = bid & 7;
    const int g     = bid >> 3;
    const int n     = r8 + 8 * (g / 24);
    const int inner = g % 24;
    const int jb    = inner % 3;            // uniform j for this block
    const int m0    = jb * 128;
    const int s     = inner / 3;
    const int i0    = (s * 49) >> 3;
    const int i1    = ((s + 1) * 49) >> 3;

    const int tid = threadIdx.x;
    const int r   = tid >> 1;               // 0..127  (= c for A rows)
    const int c0  = (tid & 1) * 32;

    const int ashift = 112 * (jb - 1);
    const _Float16* xa = xh + ((size_t)n * CCH + r) * HWP;
    const _Float16* pw = p2wh + (size_t)(m0 + r) * HWP;

    const int wave = tid >> 6;
    const int lane = tid & 63;
    const int l15  = lane & 15;
    const int quad = lane >> 4;
    const int wm   = (wave >> 1) * 64;
    const int wn   = (wave & 1) * 64;

    floatx4 acc[4][4];
#pragma unroll
    for (int a = 0; a < 4; ++a)
#pragma unroll
        for (int b = 0; b < 4; ++b) acc[a][b] = (floatx4){0.f,0.f,0.f,0.f};

    half8 xv[4], wv[4], uv[4], vv[4];   // in-flight staging registers

    // ---- prologue: issue loads for it = i0 ----
    {
        const int p0 = i0 * 64;
#pragma unroll
        for (int seg = 0; seg < 4; ++seg) {
            const int col  = c0 + seg * 8;
            const int pA   = p0 + col;
            const int srcp = pA + ashift;          // 8-aligned run: wholly in/out
            if (srcp >= 0 && srcp < HWP) {
                xv[seg] = *(const half8*)(xa + srcp);
                wv[seg] = *(const half8*)(pw + pA);
            } else {
#pragma unroll
                for (int i = 0; i < 8; ++i) { xv[seg][i] = (_Float16)0.f; wv[seg][i] = (_Float16)0.f; }
            }
            const int proll = (pA >= WWD) ? (pA - WWD) : (pA + (HH - 1) * WWD);
            uv[seg] = *(const half8*)(xa + pA);
            vv[seg] = *(const half8*)(xa + proll);
        }
    }

    for (int it = i0; it < i1; ++it) {
        // ---- commit staging regs to LDS (waitcnt on in-flight loads) ----
#pragma unroll
        for (int seg = 0; seg < 4; ++seg) {
            const int col = c0 + seg * 8;
            *(half8*)(&As[r * 72 + col]) = xv[seg] * wv[seg];  // t2' = p2w' * x(shifted)
            *(half8*)(&Bs[r * 72 + col]) = uv[seg] + vv[seg];  // t6 = x + roll(x)
        }
        __syncthreads();
        // ---- issue next iteration's loads: overlap with MFMA phase below ----
        if (it + 1 < i1) {
            const int p0 = (it + 1) * 64;
#pragma unroll
            for (int seg = 0; seg < 4; ++seg) {
                const int col  = c0 + seg * 8;
                const int pA   = p0 + col;
                const int srcp = pA + ashift;
                if (srcp >= 0 && srcp < HWP) {
                    xv[seg] = *(const half8*)(xa + srcp);
                    wv[seg] = *(const half8*)(pw + pA);
                } else {
#pragma unroll
                    for (int i = 0; i < 8; ++i) { xv[seg][i] = (_Float16)0.f; wv[seg][i] = (_Float16)0.f; }
                }
                const int proll = (pA >= WWD) ? (pA - WWD) : (pA + (HH - 1) * WWD);
                uv[seg] = *(const half8*)(xa + pA);
                vv[seg] = *(const half8*)(xa + proll);
            }
        }
        // ---- MFMA on current LDS tile ----
#pragma unroll
        for (int ks = 0; ks < 2; ++ks) {
            const int ko = ks * 32 + quad * 8;
            half8 af[4], bf[4];
#pragma unroll
            for (int mi = 0; mi < 4; ++mi) af[mi] = *(half8*)(&As[(wm + mi * 16 + l15) * 72 + ko]);
#pragma unroll
            for (int ni = 0; ni < 4; ++ni) bf[ni] = *(half8*)(&Bs[(wn + ni * 16 + l15) * 72 + ko]);
#pragma unroll
            for (int mi = 0; mi < 4; ++mi)
#pragma unroll
                for (int ni = 0; ni < 4; ++ni)
                    acc[mi][ni] = __builtin_amdgcn_mfma_f32_16x16x32_f16(af[mi], bf[ni], acc[mi][ni], 0, 0, 0);
        }
        __syncthreads();
    }

    _Float16* pbase = part + (size_t)(s * NB + n) * K3C * CCH;
#pragma unroll
    for (int mi = 0; mi < 4; ++mi)
#pragma unroll
        for (int ni = 0; ni < 4; ++ni) {
            const int kr = m0 + wm + mi * 16 + quad * 4;
            const int cc = wn + ni * 16 + l15;
#pragma unroll
            for (int r2 = 0; r2 < 4; ++r2)
                pbase[(size_t)(kr + r2) * CCH + cc] = (_Float16)acc[mi][ni][r2];
        }
}

// ---------------- reduce: t7T[n][c2][k'] = (1/56) * sum_s part[s][n][k'][c2] ----------------
__global__ __launch_bounds__(256) void reduce_kernel(const _Float16* __restrict__ part,
                                                     _Float16* __restrict__ t7T) {
    __shared__ _Float16 tile[16][130];
    const int n  = blockIdx.y;
    const int k0 = blockIdx.x * 16;
    const int t  = threadIdx.x;
    const int c2 = t & 127;
    const int kh = t >> 7;
#pragma unroll
    for (int kk = 0; kk < 8; ++kk) {
        const int k = kh * 8 + kk;
        float sum = 0.f;
#pragma unroll
        for (int sp = 0; sp < SPLITK; ++sp)
            sum += (float)part[(((size_t)sp * NB + n) * K3C + k0 + k) * CCH + c2];
        tile[k][c2] = (_Float16)(sum * (1.0f / 56.0f));
    }
    __syncthreads();
    const int kt = t & 15;
    const int c0 = t >> 4;
#pragma unroll
    for (int cc = 0; cc < 8; ++cc) {
        const int cw = c0 * 8 + cc;
        t7T[((size_t)n * CCH + cw) * K3C + k0 + kt] = tile[kt][cw];
    }
}

// ---------------- GEMM2 (permuted K, reg-prefetch pipeline) ----------------
// out[n,c2,p] = t8*x + sc * sum_k' t7T[c2,k']*t3'[k',p]; t3'[j*128+c, p] = xT[p_shift(j)][c].
__global__ __launch_bounds__(256) void gemm2_kernel(const _Float16* __restrict__ xh,
                                                    const _Float16* __restrict__ xT,
                                                    const _Float16* __restrict__ t7T,
                                                    const float* __restrict__ t8,
                                                    float* __restrict__ out) {
    __shared__ _Float16 As[128 * 72];   // [c2][k_local]
    __shared__ _Float16 Bs[64 * 72];    // [p][k_local]

    const int bid = blockIdx.x;
    const int r8  = bid & 7;
    const int g   = bid >> 3;
    const int n   = r8 + 8 * (g / 49);
    const int pt0 = (g % 49) * 64;
    const int tid = threadIdx.x;

    // A staging: 2 threads/row, 4 half8 per iter
    const int ar = tid >> 1;
    const int ac = (tid & 1) * 32;
    const _Float16* asrc = t7T + ((size_t)n * CCH + ar) * K3C;

    // B staging: row rb (p_local), 16 f16 seg
    const int rb   = tid >> 2;          // 0..63
    const int bseg = (tid & 3) * 16;
    const int pB   = pt0 + rb;
    const int hb   = pB / WWD;
    const int wb   = pB - hb * WWD;
    const _Float16* xTn = xT + (size_t)n * HWP * CCH;

    const int wave = tid >> 6;
    const int lane = tid & 63;
    const int l15  = lane & 15;
    const int quad = lane >> 4;
    const int wm   = (wave >> 1) * 64;
    const int wn   = (wave & 1) * 32;

    floatx4 acc[4][2];
#pragma unroll
    for (int a = 0; a < 4; ++a)
#pragma unroll
        for (int b = 0; b < 2; ++b) acc[a][b] = (floatx4){0.f,0.f,0.f,0.f};

    half8 av[4], bv0, bv1;   // in-flight staging registers

    // ---- prologue: issue loads for k0 = 0 ----
    {
#pragma unroll
        for (int seg = 0; seg < 4; ++seg)
            av[seg] = *(const half8*)(asrc + ac + seg * 8);
        const int wsrc = wb - 2;        // j=0 -> shift -2
        if (wsrc >= 0) {
            const _Float16* srcB = xTn + ((size_t)hb * WWD + wsrc) * CCH + bseg;  // c0k=0
            bv0 = *(const half8*)(srcB);
            bv1 = *(const half8*)(srcB + 8);
        } else {
#pragma unroll
            for (int i = 0; i < 8; ++i) { bv0[i] = (_Float16)0.f; bv1[i] = (_Float16)0.f; }
        }
    }

#pragma unroll
    for (int k0 = 0; k0 < K3C; k0 += 64) {
        // ---- commit staging regs to LDS ----
#pragma unroll
        for (int seg = 0; seg < 4; ++seg)
            *(half8*)(&As[ar * 72 + ac + seg * 8]) = av[seg];
        *(half8*)(&Bs[rb * 72 + bseg])     = bv0;
        *(half8*)(&Bs[rb * 72 + bseg + 8]) = bv1;
        __syncthreads();
        // ---- issue next iteration's loads (overlap with MFMA) ----
        if (k0 + 64 < K3C) {
            const int kn  = k0 + 64;
            const int jn  = kn >> 7;
            const int c0k = kn & 127;
#pragma unroll
            for (int seg = 0; seg < 4; ++seg)
                av[seg] = *(const half8*)(asrc + kn + ac + seg * 8);
            const int wsrc = wb + 2 * jn - 2;
            if (wsrc >= 0 && wsrc < WWD) {
                const _Float16* srcB = xTn + ((size_t)hb * WWD + wsrc) * CCH + c0k + bseg;
                bv0 = *(const half8*)(srcB);
                bv1 = *(const half8*)(srcB + 8);
            } else {
#pragma unroll
                for (int i = 0; i < 8; ++i) { bv0[i] = (_Float16)0.f; bv1[i] = (_Float16)0.f; }
            }
        }
        // ---- MFMA ----
#pragma unroll
        for (int ks = 0; ks < 2; ++ks) {
            const int ko = ks * 32 + quad * 8;
            half8 af[4], bf[2];
#pragma unroll
            for (int mi = 0; mi < 4; ++mi) af[mi] = *(half8*)(&As[(wm + mi * 16 + l15) * 72 + ko]);
#pragma unroll
            for (int ni = 0; ni < 2; ++ni) bf[ni] = *(half8*)(&Bs[(wn + ni * 16 + l15) * 72 + ko]);
#pragma unroll
            for (int mi = 0; mi < 4; ++mi)
#pragma unroll
                for (int ni = 0; ni < 2; ++ni)
                    acc[mi][ni] = __builtin_amdgcn_mfma_f32_16x16x32_f16(af[mi], bf[ni], acc[mi][ni], 0, 0, 0);
        }
        __syncthreads();
    }

    const float sc = 0.05103103630798288f;  // 1/sqrt(384)
#pragma unroll
    for (int mi = 0; mi < 4; ++mi)
#pragma unroll
        for (int ni = 0; ni < 2; ++ni) {
            const int ccb = wm + mi * 16 + quad * 4;
            const int pp  = pt0 + wn + ni * 16 + l15;
#pragma unroll
            for (int r2 = 0; r2 < 4; ++r2) {
                const int c2 = ccb + r2;
                const size_t oidx = ((size_t)n * CCH + c2) * HWP + pp;
                const float t9 = t8[((size_t)n * 4 + (c2 & 3)) * HWP + pp] * (float)xh[oidx];
                out[oidx] = acc[mi][ni][r2] * sc + t9;
            }
        }
}

extern "C" void kernel_launch(void* const* d_in, const int* in_sizes, int n_in,
                              void* d_out, int out_size, void* d_ws, size_t ws_size,
                              hipStream_t stream) {
    const float* x      = (const float*)d_in[0];
    const float* p2w    = (const float*)d_in[1];
    const float* p5w    = (const float*)d_in[2];
    const float* conv_w = (const float*)d_in[3];
    float* out = (float*)d_out;

    // ws: xh 25.69MB | p2wh 2.41MB | t8 1.61MB | t7T 3.15MB | xT 25.69MB
    char* ws = (char*)d_ws;
    _Float16* xh   = (_Float16*)ws;
    _Float16* p2wh = (_Float16*)(ws + 25690112);
    float*    t8f  = (float*)   (ws + 25690112 + 2408448);
    _Float16* t7T  = (_Float16*)(ws + 25690112 + 2408448 + 1605632);
    _Float16* xT   = (_Float16*)(ws + 25690112 + 2408448 + 1605632 + 3145728);
    _Float16* part = (_Float16*)out;  // f16 partials (25.2MB) consumed by reduce before gemm2 writes out

    cvtp2w_kernel<<<dim3(K3C), dim3(256), 0, stream>>>(p2w, p2wh);
    cvt_xt_kernel<<<dim3(3136), dim3(256), 0, stream>>>(x, xh, xT);
    t8_kernel<<<dim3(1568), dim3(64), 0, stream>>>(xh, conv_w, p5w, t8f);
    gemm1_kernel<<<dim3(768), dim3(256), 0, stream>>>(xh, p2wh, part);
    reduce_kernel<<<dim3(24, NB), dim3(256), 0, stream>>>(part, t7T);
    gemm2_kernel<<<dim3(1568), dim3(256), 0, stream>>>(xh, xT, t7T, t8f, out);
}

// Round 2
// 180.652 us; speedup vs baseline: 1.2512x; 1.1379x over previous
//
#include <hip/hip_runtime.h>

#define NB 32
#define CCH 128
#define HH 56
#define WWD 56
#define HWP (HH*WWD)   // 3136
#define K3C (3*CCH)    // 384
#define SPLITK 8

typedef _Float16 half8 __attribute__((ext_vector_type(8)));
typedef float floatx4 __attribute__((ext_vector_type(4)));

// ---------------- prep: p2w f32 -> f16, K-permuted: row k' = j*128+c <- src row (c,j) ----------
__global__ __launch_bounds__(256) void cvtp2w_kernel(const float* __restrict__ src,
                                                     _Float16* __restrict__ dst) {
    const int row = blockIdx.x;          // k' = j*128 + c
    const int j = row >> 7;
    const int c = row & 127;
    const float* s = src + ((size_t)c * 3 + j) * HWP;
    _Float16* d = dst + (size_t)row * HWP;
    for (int base = threadIdx.x * 8; base < HWP; base += 2048) {
        const float4 a = *(const float4*)(s + base);
        const float4 b = *(const float4*)(s + base + 4);
        half8 v;
        v[0] = (_Float16)a.x; v[1] = (_Float16)a.y; v[2] = (_Float16)a.z; v[3] = (_Float16)a.w;
        v[4] = (_Float16)b.x; v[5] = (_Float16)b.y; v[6] = (_Float16)b.z; v[7] = (_Float16)b.w;
        *(half8*)(d + base) = v;
    }
}

// ---------------- fused: x f32 -> xh f16 AND xT[n][p][c] transpose (64x64 LDS tiles) ----------
// grid 3136 = 8 * (4n * 2c * 49p); XCD swizzle n%8 == bid%8
__global__ __launch_bounds__(256) void cvt_xt_kernel(const float* __restrict__ x,
                                                     _Float16* __restrict__ xh,
                                                     _Float16* __restrict__ xT) {
    __shared__ _Float16 t[64 * 72];
    const int bid = blockIdx.x;
    const int r8  = bid & 7;
    const int g   = bid >> 3;            // 0..391
    const int n   = r8 + 8 * (g / 98);
    const int rem = g % 98;
    const int c0  = (rem / 49) * 64;
    const int p0  = (rem % 49) * 64;
    const int tid = threadIdx.x;
    const int r   = tid >> 2;            // 0..63
    const int seg = (tid & 3) * 16;

    const float* src = x + ((size_t)n * CCH + c0 + r) * HWP + p0 + seg;
    const float4 a0 = *(const float4*)(src);
    const float4 a1 = *(const float4*)(src + 4);
    const float4 a2 = *(const float4*)(src + 8);
    const float4 a3 = *(const float4*)(src + 12);
    half8 v0, v1;
    v0[0] = (_Float16)a0.x; v0[1] = (_Float16)a0.y; v0[2] = (_Float16)a0.z; v0[3] = (_Float16)a0.w;
    v0[4] = (_Float16)a1.x; v0[5] = (_Float16)a1.y; v0[6] = (_Float16)a1.z; v0[7] = (_Float16)a1.w;
    v1[0] = (_Float16)a2.x; v1[1] = (_Float16)a2.y; v1[2] = (_Float16)a2.z; v1[3] = (_Float16)a2.w;
    v1[4] = (_Float16)a3.x; v1[5] = (_Float16)a3.y; v1[6] = (_Float16)a3.z; v1[7] = (_Float16)a3.w;

    _Float16* dxh = xh + ((size_t)n * CCH + c0 + r) * HWP + p0 + seg;
    *(half8*)(dxh)     = v0;
    *(half8*)(dxh + 8) = v1;
    *(half8*)(&t[r * 72 + seg])     = v0;
    *(half8*)(&t[r * 72 + seg + 8]) = v1;
    __syncthreads();
    // write rows of xT: p_local = r, c chunk = seg..seg+15
    _Float16* dst = xT + ((size_t)n * HWP + p0 + r) * CCH + c0 + seg;
    half8 w0, w1;
#pragma unroll
    for (int i = 0; i < 8; ++i) w0[i] = t[(seg + i) * 72 + r];
#pragma unroll
    for (int i = 0; i < 8; ++i) w1[i] = t[(seg + 8 + i) * 72 + r];
    *(half8*)(dst) = w0;
    *(half8*)(dst + 8) = w1;
}

// ---------------- t8 via xT (coalesced): t8[n,o,p] = sum_c w[o,c]*xT[n,proll(p),c] ------------
// w[o,c] = conv_w[o,c]*p5w[c]. Stage 64 xT rows (contiguous in p) into LDS, then dot per (o,p).
__global__ __launch_bounds__(256) void t8_kernel(const _Float16* __restrict__ xT,
                                                 const float* __restrict__ conv_w,
                                                 const float* __restrict__ p5w,
                                                 float* __restrict__ t8) {
    __shared__ _Float16 tile[64 * 136];   // [p_local][c], stride 136 f16 (16B-aligned rows)
    __shared__ float wf[4 * 128];
    const int bid = blockIdx.x;
    const int r8  = bid & 7;
    const int g   = bid >> 3;
    const int n   = r8 + 8 * (g / 49);
    const int p0  = (g % 49) * 64;
    const int tid = threadIdx.x;

    wf[tid]       = conv_w[tid] * p5w[tid & 127];
    wf[tid + 256] = conv_w[tid + 256] * p5w[tid & 127];

    const int coff = (tid & 15) * 8;      // 0..120
    const _Float16* xTn = xT + (size_t)n * HWP * CCH;
#pragma unroll
    for (int q = 0; q < 4; ++q) {
        const int row = q * 16 + (tid >> 4);             // 0..63
        const int p   = p0 + row;
        const int srcrow = (p >= WWD) ? (p - WWD) : (p + (HH - 1) * WWD);
        *(half8*)(&tile[row * 136 + coff]) = *(const half8*)(xTn + (size_t)srcrow * CCH + coff);
    }
    __syncthreads();

    const int o  = tid >> 6;              // wave-uniform
    const int pl = tid & 63;
    const float* wrow = wf + o * 128;
    float a = 0.f;
#pragma unroll
    for (int cs = 0; cs < 16; ++cs) {
        const half8 v = *(const half8*)(&tile[pl * 136 + cs * 8]);
#pragma unroll
        for (int i = 0; i < 8; ++i) a += wrow[cs * 8 + i] * (float)v[i];
    }
    t8[((size_t)n * 4 + o) * HWP + p0 + pl] = a;
}

// ---------------- GEMM1 (split-K, permuted K, f16 partials, coalesced staging) ----------
// k' = j*128+c; m0-block has uniform j. Tm=128, Tn=128, BK=64; grid 768; swizzle n%8==bid%8.
// Staging map: row = s*32 + (tid>>3), col = (tid&7)*8 -> each wave-instr reads 8 rows x 128B.
__global__ __launch_bounds__(256) void gemm1_kernel(const _Float16* __restrict__ xh,
                                                    const _Float16* __restrict__ p2wh,
                                                    _Float16* __restrict__ part) {
    __shared__ _Float16 As[128 * 72];
    __shared__ _Float16 Bs[128 * 72];

    const int bid   = blockIdx.x;
    const int r8    = bid & 7;
    const int g     = bid >> 3;
    const int n     = r8 + 8 * (g / 24);
    const int inner = g % 24;
    const int jb    = inner % 3;            // uniform j for this block
    const int m0    = jb * 128;
    const int s     = inner / 3;
    const int i0    = (s * 49) >> 3;
    const int i1    = ((s + 1) * 49) >> 3;

    const int tid  = threadIdx.x;
    const int lrow = tid >> 3;              // 0..31
    const int lcol = (tid & 7) * 8;         // 0..56

    const int ashift = 112 * (jb - 1);
    const _Float16* xh_n = xh + (size_t)n * CCH * HWP;
    const _Float16* pw_m = p2wh + (size_t)m0 * HWP;

    const int wave = tid >> 6;
    const int lane = tid & 63;
    const int l15  = lane & 15;
    const int quad = lane >> 4;
    const int wm   = (wave >> 1) * 64;
    const int wn   = (wave & 1) * 64;

    floatx4 acc[4][4];
#pragma unroll
    for (int a = 0; a < 4; ++a)
#pragma unroll
        for (int b = 0; b < 4; ++b) acc[a][b] = (floatx4){0.f,0.f,0.f,0.f};

    half8 xv[4], wv[4], uv[4], vv[4];   // in-flight staging registers

    // ---- prologue: issue loads for it = i0 ----
    {
        const int p0 = i0 * 64;
        const int pA = p0 + lcol;
        const int srcp  = pA + ashift;
        const int proll = (pA >= WWD) ? (pA - WWD) : (pA + (HH - 1) * WWD);
        const bool ok = (srcp >= 0 && srcp < HWP);
#pragma unroll
        for (int sg = 0; sg < 4; ++sg) {
            const int row = sg * 32 + lrow;
            const _Float16* xaS = xh_n + (size_t)row * HWP;
            if (ok) xv[sg] = *(const half8*)(xaS + srcp);
            else { half8 z; for (int i = 0; i < 8; ++i) z[i] = (_Float16)0.f; xv[sg] = z; }
            wv[sg] = *(const half8*)(pw_m + (size_t)row * HWP + pA);
            uv[sg] = *(const half8*)(xaS + pA);
            vv[sg] = *(const half8*)(xaS + proll);
        }
    }

    for (int it = i0; it < i1; ++it) {
        // ---- commit staging regs to LDS ----
#pragma unroll
        for (int sg = 0; sg < 4; ++sg) {
            const int row = sg * 32 + lrow;
            *(half8*)(&As[row * 72 + lcol]) = xv[sg] * wv[sg];  // t2' = p2w' * x(shifted)
            *(half8*)(&Bs[row * 72 + lcol]) = uv[sg] + vv[sg];  // t6 = x + roll(x)
        }
        __syncthreads();
        // ---- issue next iteration's loads (overlap with MFMA) ----
        if (it + 1 < i1) {
            const int p0 = (it + 1) * 64;
            const int pA = p0 + lcol;
            const int srcp  = pA + ashift;
            const int proll = (pA >= WWD) ? (pA - WWD) : (pA + (HH - 1) * WWD);
            const bool ok = (srcp >= 0 && srcp < HWP);
#pragma unroll
            for (int sg = 0; sg < 4; ++sg) {
                const int row = sg * 32 + lrow;
                const _Float16* xaS = xh_n + (size_t)row * HWP;
                if (ok) xv[sg] = *(const half8*)(xaS + srcp);
                else { half8 z; for (int i = 0; i < 8; ++i) z[i] = (_Float16)0.f; xv[sg] = z; }
                wv[sg] = *(const half8*)(pw_m + (size_t)row * HWP + pA);
                uv[sg] = *(const half8*)(xaS + pA);
                vv[sg] = *(const half8*)(xaS + proll);
            }
        }
        // ---- MFMA on current LDS tile ----
#pragma unroll
        for (int ks = 0; ks < 2; ++ks) {
            const int ko = ks * 32 + quad * 8;
            half8 af[4], bf[4];
#pragma unroll
            for (int mi = 0; mi < 4; ++mi) af[mi] = *(half8*)(&As[(wm + mi * 16 + l15) * 72 + ko]);
#pragma unroll
            for (int ni = 0; ni < 4; ++ni) bf[ni] = *(half8*)(&Bs[(wn + ni * 16 + l15) * 72 + ko]);
#pragma unroll
            for (int mi = 0; mi < 4; ++mi)
#pragma unroll
                for (int ni = 0; ni < 4; ++ni)
                    acc[mi][ni] = __builtin_amdgcn_mfma_f32_16x16x32_f16(af[mi], bf[ni], acc[mi][ni], 0, 0, 0);
        }
        __syncthreads();
    }

    _Float16* pbase = part + (size_t)(s * NB + n) * K3C * CCH;
#pragma unroll
    for (int mi = 0; mi < 4; ++mi)
#pragma unroll
        for (int ni = 0; ni < 4; ++ni) {
            const int kr = m0 + wm + mi * 16 + quad * 4;
            const int cc = wn + ni * 16 + l15;
#pragma unroll
            for (int r2 = 0; r2 < 4; ++r2)
                pbase[(size_t)(kr + r2) * CCH + cc] = (_Float16)acc[mi][ni][r2];
        }
}

// ---------------- reduce: t7T[n][c2][k'] = (1/56) * sum_s part[s][n][k'][c2] ----------------
__global__ __launch_bounds__(256) void reduce_kernel(const _Float16* __restrict__ part,
                                                     _Float16* __restrict__ t7T) {
    __shared__ _Float16 tile[16][130];
    const int n  = blockIdx.y;
    const int k0 = blockIdx.x * 16;
    const int t  = threadIdx.x;
    const int c2 = t & 127;
    const int kh = t >> 7;
#pragma unroll
    for (int kk = 0; kk < 8; ++kk) {
        const int k = kh * 8 + kk;
        float sum = 0.f;
#pragma unroll
        for (int sp = 0; sp < SPLITK; ++sp)
            sum += (float)part[(((size_t)sp * NB + n) * K3C + k0 + k) * CCH + c2];
        tile[k][c2] = (_Float16)(sum * (1.0f / 56.0f));
    }
    __syncthreads();
    const int kt = t & 15;
    const int c0 = t >> 4;
#pragma unroll
    for (int cc = 0; cc < 8; ++cc) {
        const int cw = c0 * 8 + cc;
        t7T[((size_t)n * CCH + cw) * K3C + k0 + kt] = tile[kt][cw];
    }
}

// ---------------- GEMM2 (permuted K, coalesced staging, reg-prefetch) ----------------
// out[n,c2,p] = t8*x + sc * sum_k' t7T[c2,k']*t3'[k',p]; t3'[j*128+c, p] = xT[p_shift(j)][c].
__global__ __launch_bounds__(256) void gemm2_kernel(const _Float16* __restrict__ xh,
                                                    const _Float16* __restrict__ xT,
                                                    const _Float16* __restrict__ t7T,
                                                    const float* __restrict__ t8,
                                                    float* __restrict__ out) {
    __shared__ _Float16 As[128 * 72];   // [c2][k_local]
    __shared__ _Float16 Bs[64 * 72];    // [p][k_local]

    const int bid = blockIdx.x;
    const int r8  = bid & 7;
    const int g   = bid >> 3;
    const int n   = r8 + 8 * (g / 49);
    const int pt0 = (g % 49) * 64;
    const int tid = threadIdx.x;

    const int lrow = tid >> 3;          // 0..31
    const int lcol = (tid & 7) * 8;     // 0..56

    const _Float16* t7n = t7T + (size_t)n * CCH * K3C;
    const _Float16* xTn = xT + (size_t)n * HWP * CCH;

    // B row geometry (per s=0,1): prow = pt0 + s*32 + lrow
    int hbArr[2], wbArr[2];
#pragma unroll
    for (int sg = 0; sg < 2; ++sg) {
        const int prow = pt0 + sg * 32 + lrow;
        hbArr[sg] = prow / WWD;
        wbArr[sg] = prow - hbArr[sg] * WWD;
    }

    const int wave = tid >> 6;
    const int lane = tid & 63;
    const int l15  = lane & 15;
    const int quad = lane >> 4;
    const int wm   = (wave >> 1) * 64;
    const int wn   = (wave & 1) * 32;

    floatx4 acc[4][2];
#pragma unroll
    for (int a = 0; a < 4; ++a)
#pragma unroll
        for (int b = 0; b < 2; ++b) acc[a][b] = (floatx4){0.f,0.f,0.f,0.f};

    half8 av[4], bv[2];   // in-flight staging registers

    // ---- prologue: issue loads for k0 = 0 (j=0, c0k=0) ----
    {
#pragma unroll
        for (int sg = 0; sg < 4; ++sg)
            av[sg] = *(const half8*)(t7n + (size_t)(sg * 32 + lrow) * K3C + lcol);
#pragma unroll
        for (int sg = 0; sg < 2; ++sg) {
            const int wsrc = wbArr[sg] - 2;
            if (wsrc >= 0) {
                bv[sg] = *(const half8*)(xTn + ((size_t)hbArr[sg] * WWD + wsrc) * CCH + lcol);
            } else {
                half8 z; for (int i = 0; i < 8; ++i) z[i] = (_Float16)0.f; bv[sg] = z;
            }
        }
    }

#pragma unroll
    for (int k0 = 0; k0 < K3C; k0 += 64) {
        // ---- commit staging regs to LDS ----
#pragma unroll
        for (int sg = 0; sg < 4; ++sg)
            *(half8*)(&As[(sg * 32 + lrow) * 72 + lcol]) = av[sg];
#pragma unroll
        for (int sg = 0; sg < 2; ++sg)
            *(half8*)(&Bs[(sg * 32 + lrow) * 72 + lcol]) = bv[sg];
        __syncthreads();
        // ---- issue next iteration's loads (overlap with MFMA) ----
        if (k0 + 64 < K3C) {
            const int kn  = k0 + 64;
            const int jn  = kn >> 7;
            const int c0k = kn & 127;
#pragma unroll
            for (int sg = 0; sg < 4; ++sg)
                av[sg] = *(const half8*)(t7n + (size_t)(sg * 32 + lrow) * K3C + kn + lcol);
#pragma unroll
            for (int sg = 0; sg < 2; ++sg) {
                const int wsrc = wbArr[sg] + 2 * jn - 2;
                if (wsrc >= 0 && wsrc < WWD) {
                    bv[sg] = *(const half8*)(xTn + ((size_t)hbArr[sg] * WWD + wsrc) * CCH + c0k + lcol);
                } else {
                    half8 z; for (int i = 0; i < 8; ++i) z[i] = (_Float16)0.f; bv[sg] = z;
                }
            }
        }
        // ---- MFMA ----
#pragma unroll
        for (int ks = 0; ks < 2; ++ks) {
            const int ko = ks * 32 + quad * 8;
            half8 af[4], bf[2];
#pragma unroll
            for (int mi = 0; mi < 4; ++mi) af[mi] = *(half8*)(&As[(wm + mi * 16 + l15) * 72 + ko]);
#pragma unroll
            for (int ni = 0; ni < 2; ++ni) bf[ni] = *(half8*)(&Bs[(wn + ni * 16 + l15) * 72 + ko]);
#pragma unroll
            for (int mi = 0; mi < 4; ++mi)
#pragma unroll
                for (int ni = 0; ni < 2; ++ni)
                    acc[mi][ni] = __builtin_amdgcn_mfma_f32_16x16x32_f16(af[mi], bf[ni], acc[mi][ni], 0, 0, 0);
        }
        __syncthreads();
    }

    const float sc = 0.05103103630798288f;  // 1/sqrt(384)
#pragma unroll
    for (int mi = 0; mi < 4; ++mi)
#pragma unroll
        for (int ni = 0; ni < 2; ++ni) {
            const int ccb = wm + mi * 16 + quad * 4;
            const int pp  = pt0 + wn + ni * 16 + l15;
#pragma unroll
            for (int r2 = 0; r2 < 4; ++r2) {
                const int c2 = ccb + r2;
                const size_t oidx = ((size_t)n * CCH + c2) * HWP + pp;
                const float t9 = t8[((size_t)n * 4 + (c2 & 3)) * HWP + pp] * (float)xh[oidx];
                out[oidx] = acc[mi][ni][r2] * sc + t9;
            }
        }
}

extern "C" void kernel_launch(void* const* d_in, const int* in_sizes, int n_in,
                              void* d_out, int out_size, void* d_ws, size_t ws_size,
                              hipStream_t stream) {
    const float* x      = (const float*)d_in[0];
    const float* p2w    = (const float*)d_in[1];
    const float* p5w    = (const float*)d_in[2];
    const float* conv_w = (const float*)d_in[3];
    float* out = (float*)d_out;

    // ws: xh 25.69MB | p2wh 2.41MB | t8 1.61MB | t7T 3.15MB | xT 25.69MB
    char* ws = (char*)d_ws;
    _Float16* xh   = (_Float16*)ws;
    _Float16* p2wh = (_Float16*)(ws + 25690112);
    float*    t8f  = (float*)   (ws + 25690112 + 2408448);
    _Float16* t7T  = (_Float16*)(ws + 25690112 + 2408448 + 1605632);
    _Float16* xT   = (_Float16*)(ws + 25690112 + 2408448 + 1605632 + 3145728);
    _Float16* part = (_Float16*)out;  // f16 partials (25.2MB) consumed by reduce before gemm2 writes out

    cvtp2w_kernel<<<dim3(K3C), dim3(256), 0, stream>>>(p2w, p2wh);
    cvt_xt_kernel<<<dim3(3136), dim3(256), 0, stream>>>(x, xh, xT);
    t8_kernel<<<dim3(1568), dim3(256), 0, stream>>>(xT, conv_w, p5w, t8f);
    gemm1_kernel<<<dim3(768), dim3(256), 0, stream>>>(xh, p2wh, part);
    reduce_kernel<<<dim3(24, NB), dim3(256), 0, stream>>>(part, t7T);
    gemm2_kernel<<<dim3(1568), dim3(256), 0, stream>>>(xh, xT, t7T, t8f, out);
}

// Round 4
// 179.866 us; speedup vs baseline: 1.2566x; 1.0044x over previous
//
#include <hip/hip_runtime.h>

#define NB 32
#define CCH 128
#define HH 56
#define WWD 56
#define HWP (HH*WWD)   // 3136
#define K3C (3*CCH)    // 384
#define SPLITK 8

typedef _Float16 half8 __attribute__((ext_vector_type(8)));
typedef float floatx4 __attribute__((ext_vector_type(4)));

// ---------------- prep: p2w f32 -> f16, K-permuted: row k' = j*128+c <- src row (c,j) ----------
__global__ __launch_bounds__(256) void cvtp2w_kernel(const float* __restrict__ src,
                                                     _Float16* __restrict__ dst) {
    const int row = blockIdx.x;          // k' = j*128 + c
    const int j = row >> 7;
    const int c = row & 127;
    const float* s = src + ((size_t)c * 3 + j) * HWP;
    _Float16* d = dst + (size_t)row * HWP;
    for (int base = threadIdx.x * 8; base < HWP; base += 2048) {
        const float4 a = *(const float4*)(s + base);
        const float4 b = *(const float4*)(s + base + 4);
        half8 v;
        v[0] = (_Float16)a.x; v[1] = (_Float16)a.y; v[2] = (_Float16)a.z; v[3] = (_Float16)a.w;
        v[4] = (_Float16)b.x; v[5] = (_Float16)b.y; v[6] = (_Float16)b.z; v[7] = (_Float16)b.w;
        *(half8*)(d + base) = v;
    }
}

// ---------------- fused: x f32 -> xh f16 AND xT[n][p][c] transpose (64x64 LDS tiles) ----------
// grid 3136 = 8 * (4n * 2c * 49p); XCD swizzle n%8 == bid%8
__global__ __launch_bounds__(256) void cvt_xt_kernel(const float* __restrict__ x,
                                                     _Float16* __restrict__ xh,
                                                     _Float16* __restrict__ xT) {
    __shared__ _Float16 t[64 * 72];
    const int bid = blockIdx.x;
    const int r8  = bid & 7;
    const int g   = bid >> 3;            // 0..391
    const int n   = r8 + 8 * (g / 98);
    const int rem = g % 98;
    const int c0  = (rem / 49) * 64;
    const int p0  = (rem % 49) * 64;
    const int tid = threadIdx.x;
    const int r   = tid >> 2;            // 0..63
    const int seg = (tid & 3) * 16;

    const float* src = x + ((size_t)n * CCH + c0 + r) * HWP + p0 + seg;
    const float4 a0 = *(const float4*)(src);
    const float4 a1 = *(const float4*)(src + 4);
    const float4 a2 = *(const float4*)(src + 8);
    const float4 a3 = *(const float4*)(src + 12);
    half8 v0, v1;
    v0[0] = (_Float16)a0.x; v0[1] = (_Float16)a0.y; v0[2] = (_Float16)a0.z; v0[3] = (_Float16)a0.w;
    v0[4] = (_Float16)a1.x; v0[5] = (_Float16)a1.y; v0[6] = (_Float16)a1.z; v0[7] = (_Float16)a1.w;
    v1[0] = (_Float16)a2.x; v1[1] = (_Float16)a2.y; v1[2] = (_Float16)a2.z; v1[3] = (_Float16)a2.w;
    v1[4] = (_Float16)a3.x; v1[5] = (_Float16)a3.y; v1[6] = (_Float16)a3.z; v1[7] = (_Float16)a3.w;

    _Float16* dxh = xh + ((size_t)n * CCH + c0 + r) * HWP + p0 + seg;
    *(half8*)(dxh)     = v0;
    *(half8*)(dxh + 8) = v1;
    *(half8*)(&t[r * 72 + seg])     = v0;
    *(half8*)(&t[r * 72 + seg + 8]) = v1;
    __syncthreads();
    // write rows of xT: p_local = r, c chunk = seg..seg+15
    _Float16* dst = xT + ((size_t)n * HWP + p0 + r) * CCH + c0 + seg;
    half8 w0, w1;
#pragma unroll
    for (int i = 0; i < 8; ++i) w0[i] = t[(seg + i) * 72 + r];
#pragma unroll
    for (int i = 0; i < 8; ++i) w1[i] = t[(seg + 8 + i) * 72 + r];
    *(half8*)(dst) = w0;
    *(half8*)(dst + 8) = w1;
}

// ---------------- GEMM1 (split-K, permuted K, f16 partials, coalesced staging) ----------
// k' = j*128+c; m0-block has uniform j. Tm=128, Tn=128, BK=64; grid 768; swizzle n%8==bid%8.
// Staging map: row = s*32 + (tid>>3), col = (tid&7)*8 -> each wave-instr reads 8 rows x 128B.
__global__ __launch_bounds__(256) void gemm1_kernel(const _Float16* __restrict__ xh,
                                                    const _Float16* __restrict__ p2wh,
                                                    _Float16* __restrict__ part) {
    __shared__ _Float16 As[128 * 72];
    __shared__ _Float16 Bs[128 * 72];

    const int bid   = blockIdx.x;
    const int r8    = bid & 7;
    const int g     = bid >> 3;
    const int n     = r8 + 8 * (g / 24);
    const int inner = g % 24;
    const int jb    = inner % 3;            // uniform j for this block
    const int m0    = jb * 128;
    const int s     = inner / 3;
    const int i0    = (s * 49) >> 3;
    const int i1    = ((s + 1) * 49) >> 3;

    const int tid  = threadIdx.x;
    const int lrow = tid >> 3;              // 0..31
    const int lcol = (tid & 7) * 8;         // 0..56

    const int ashift = 112 * (jb - 1);
    const _Float16* xh_n = xh + (size_t)n * CCH * HWP;
    const _Float16* pw_m = p2wh + (size_t)m0 * HWP;

    const int wave = tid >> 6;
    const int lane = tid & 63;
    const int l15  = lane & 15;
    const int quad = lane >> 4;
    const int wm   = (wave >> 1) * 64;
    const int wn   = (wave & 1) * 64;

    floatx4 acc[4][4];
#pragma unroll
    for (int a = 0; a < 4; ++a)
#pragma unroll
        for (int b = 0; b < 4; ++b) acc[a][b] = (floatx4){0.f,0.f,0.f,0.f};

    half8 xv[4], wv[4], uv[4], vv[4];   // in-flight staging registers

    // ---- prologue: issue loads for it = i0 ----
    {
        const int p0 = i0 * 64;
        const int pA = p0 + lcol;
        const int srcp  = pA + ashift;
        const int proll = (pA >= WWD) ? (pA - WWD) : (pA + (HH - 1) * WWD);
        const bool ok = (srcp >= 0 && srcp < HWP);
#pragma unroll
        for (int sg = 0; sg < 4; ++sg) {
            const int row = sg * 32 + lrow;
            const _Float16* xaS = xh_n + (size_t)row * HWP;
            if (ok) xv[sg] = *(const half8*)(xaS + srcp);
            else { half8 z; for (int i = 0; i < 8; ++i) z[i] = (_Float16)0.f; xv[sg] = z; }
            wv[sg] = *(const half8*)(pw_m + (size_t)row * HWP + pA);
            uv[sg] = *(const half8*)(xaS + pA);
            vv[sg] = *(const half8*)(xaS + proll);
        }
    }

    for (int it = i0; it < i1; ++it) {
        // ---- commit staging regs to LDS ----
#pragma unroll
        for (int sg = 0; sg < 4; ++sg) {
            const int row = sg * 32 + lrow;
            *(half8*)(&As[row * 72 + lcol]) = xv[sg] * wv[sg];  // t2' = p2w' * x(shifted)
            *(half8*)(&Bs[row * 72 + lcol]) = uv[sg] + vv[sg];  // t6 = x + roll(x)
        }
        __syncthreads();
        // ---- issue next iteration's loads (overlap with MFMA) ----
        if (it + 1 < i1) {
            const int p0 = (it + 1) * 64;
            const int pA = p0 + lcol;
            const int srcp  = pA + ashift;
            const int proll = (pA >= WWD) ? (pA - WWD) : (pA + (HH - 1) * WWD);
            const bool ok = (srcp >= 0 && srcp < HWP);
#pragma unroll
            for (int sg = 0; sg < 4; ++sg) {
                const int row = sg * 32 + lrow;
                const _Float16* xaS = xh_n + (size_t)row * HWP;
                if (ok) xv[sg] = *(const half8*)(xaS + srcp);
                else { half8 z; for (int i = 0; i < 8; ++i) z[i] = (_Float16)0.f; xv[sg] = z; }
                wv[sg] = *(const half8*)(pw_m + (size_t)row * HWP + pA);
                uv[sg] = *(const half8*)(xaS + pA);
                vv[sg] = *(const half8*)(xaS + proll);
            }
        }
        // ---- MFMA on current LDS tile ----
#pragma unroll
        for (int ks = 0; ks < 2; ++ks) {
            const int ko = ks * 32 + quad * 8;
            half8 af[4], bf[4];
#pragma unroll
            for (int mi = 0; mi < 4; ++mi) af[mi] = *(half8*)(&As[(wm + mi * 16 + l15) * 72 + ko]);
#pragma unroll
            for (int ni = 0; ni < 4; ++ni) bf[ni] = *(half8*)(&Bs[(wn + ni * 16 + l15) * 72 + ko]);
#pragma unroll
            for (int mi = 0; mi < 4; ++mi)
#pragma unroll
                for (int ni = 0; ni < 4; ++ni)
                    acc[mi][ni] = __builtin_amdgcn_mfma_f32_16x16x32_f16(af[mi], bf[ni], acc[mi][ni], 0, 0, 0);
        }
        __syncthreads();
    }

    _Float16* pbase = part + (size_t)(s * NB + n) * K3C * CCH;
#pragma unroll
    for (int mi = 0; mi < 4; ++mi)
#pragma unroll
        for (int ni = 0; ni < 4; ++ni) {
            const int kr = m0 + wm + mi * 16 + quad * 4;
            const int cc = wn + ni * 16 + l15;
#pragma unroll
            for (int r2 = 0; r2 < 4; ++r2)
                pbase[(size_t)(kr + r2) * CCH + cc] = (_Float16)acc[mi][ni][r2];
        }
}

// ---------------- reduce: t7T[n][c2][k'] = (1/56) * sum_s part[s][n][k'][c2] ----------------
__global__ __launch_bounds__(256) void reduce_kernel(const _Float16* __restrict__ part,
                                                     _Float16* __restrict__ t7T) {
    __shared__ _Float16 tile[16][130];
    const int n  = blockIdx.y;
    const int k0 = blockIdx.x * 16;
    const int t  = threadIdx.x;
    const int c2 = t & 127;
    const int kh = t >> 7;
#pragma unroll
    for (int kk = 0; kk < 8; ++kk) {
        const int k = kh * 8 + kk;
        float sum = 0.f;
#pragma unroll
        for (int sp = 0; sp < SPLITK; ++sp)
            sum += (float)part[(((size_t)sp * NB + n) * K3C + k0 + k) * CCH + c2];
        tile[k][c2] = (_Float16)(sum * (1.0f / 56.0f));
    }
    __syncthreads();
    const int kt = t & 15;
    const int c0 = t >> 4;
#pragma unroll
    for (int cc = 0; cc < 8; ++cc) {
        const int cw = c0 * 8 + cc;
        t7T[((size_t)n * CCH + cw) * K3C + k0 + kt] = tile[kt][cw];
    }
}

// ---------------- GEMM2 (permuted K, coalesced staging, reg-prefetch, fused t8) ----------------
// out[n,c2,p] = t8tile*x + sc * sum_k' t7T[c2,k']*t3'[k',p]; t3'[j*128+c, p] = xT[p_shift(j)][c].
// Phase 0: t8tile[o][pl] = sum_c conv_w[o,c]*p5w[c]*xT[roll(pt0+pl)][c]  (As reused as scratch).
__global__ __launch_bounds__(256) void gemm2_kernel(const _Float16* __restrict__ xh,
                                                    const _Float16* __restrict__ xT,
                                                    const _Float16* __restrict__ t7T,
                                                    const float* __restrict__ conv_w,
                                                    const float* __restrict__ p5w,
                                                    float* __restrict__ out) {
    __shared__ _Float16 As[128 * 72];   // [c2][k_local]; phase 0: scratch [p_local][c] stride 136
    __shared__ _Float16 Bs[64 * 72];    // [p][k_local]
    __shared__ float t8tile[4 * 64];    // [o][p_local]
    __shared__ float wf[4 * 128];       // conv_w * p5w

    const int bid = blockIdx.x;
    const int r8  = bid & 7;
    const int g   = bid >> 3;
    const int n   = r8 + 8 * (g / 49);
    const int pt0 = (g % 49) * 64;
    const int tid = threadIdx.x;

    const int lrow = tid >> 3;          // 0..31
    const int lcol = (tid & 7) * 8;     // 0..56

    const _Float16* t7n = t7T + (size_t)n * CCH * K3C;
    const _Float16* xTn = xT + (size_t)n * HWP * CCH;

    // B row geometry (per s=0,1): prow = pt0 + s*32 + lrow
    int hbArr[2], wbArr[2];
#pragma unroll
    for (int sg = 0; sg < 2; ++sg) {
        const int prow = pt0 + sg * 32 + lrow;
        hbArr[sg] = prow / WWD;
        wbArr[sg] = prow - hbArr[sg] * WWD;
    }

    const int wave = tid >> 6;
    const int lane = tid & 63;
    const int l15  = lane & 15;
    const int quad = lane >> 4;
    const int wm   = (wave >> 1) * 64;
    const int wn   = (wave & 1) * 32;

    floatx4 acc[4][2];
#pragma unroll
    for (int a = 0; a < 4; ++a)
#pragma unroll
        for (int b = 0; b < 2; ++b) acc[a][b] = (floatx4){0.f,0.f,0.f,0.f};

    half8 av[4], bv[2];   // in-flight staging registers

    // ---- prologue: issue k0=0 loads EARLY so they overlap phase-0 compute ----
    {
#pragma unroll
        for (int sg = 0; sg < 4; ++sg)
            av[sg] = *(const half8*)(t7n + (size_t)(sg * 32 + lrow) * K3C + lcol);
#pragma unroll
        for (int sg = 0; sg < 2; ++sg) {
            const int wsrc = wbArr[sg] - 2;
            if (wsrc >= 0) {
                bv[sg] = *(const half8*)(xTn + ((size_t)hbArr[sg] * WWD + wsrc) * CCH + lcol);
            } else {
                half8 z; for (int i = 0; i < 8; ++i) z[i] = (_Float16)0.f; bv[sg] = z;
            }
        }
    }

    // ---- phase 0: compute t8tile (reuse As as [64][136] staging scratch) ----
    {
        wf[tid]       = conv_w[tid] * p5w[tid & 127];
        wf[tid + 256] = conv_w[tid + 256] * p5w[tid & 127];
        _Float16* tr = As;
        const int coff = (tid & 15) * 8;          // 0..120
#pragma unroll
        for (int q = 0; q < 4; ++q) {
            const int row = q * 16 + (tid >> 4);  // 0..63
            const int p   = pt0 + row;
            const int srcrow = (p >= WWD) ? (p - WWD) : (p + (HH - 1) * WWD);
            *(half8*)(&tr[row * 136 + coff]) = *(const half8*)(xTn + (size_t)srcrow * CCH + coff);
        }
        __syncthreads();
        const int o  = tid >> 6;                  // wave-uniform
        const int pl = tid & 63;
        const float* wrow = wf + o * 128;
        float a = 0.f;
#pragma unroll
        for (int cs = 0; cs < 16; ++cs) {
            const half8 v = *(const half8*)(&tr[pl * 136 + cs * 8]);
#pragma unroll
            for (int i = 0; i < 8; ++i) a += wrow[cs * 8 + i] * (float)v[i];
        }
        t8tile[o * 64 + pl] = a;
        __syncthreads();   // As free again; t8tile visible
    }

#pragma unroll
    for (int k0 = 0; k0 < K3C; k0 += 64) {
        // ---- commit staging regs to LDS ----
#pragma unroll
        for (int sg = 0; sg < 4; ++sg)
            *(half8*)(&As[(sg * 32 + lrow) * 72 + lcol]) = av[sg];
#pragma unroll
        for (int sg = 0; sg < 2; ++sg)
            *(half8*)(&Bs[(sg * 32 + lrow) * 72 + lcol]) = bv[sg];
        __syncthreads();
        // ---- issue next iteration's loads (overlap with MFMA) ----
        if (k0 + 64 < K3C) {
            const int kn  = k0 + 64;
            const int jn  = kn >> 7;
            const int c0k = kn & 127;
#pragma unroll
            for (int sg = 0; sg < 4; ++sg)
                av[sg] = *(const half8*)(t7n + (size_t)(sg * 32 + lrow) * K3C + kn + lcol);
#pragma unroll
            for (int sg = 0; sg < 2; ++sg) {
                const int wsrc = wbArr[sg] + 2 * jn - 2;
                if (wsrc >= 0 && wsrc < WWD) {
                    bv[sg] = *(const half8*)(xTn + ((size_t)hbArr[sg] * WWD + wsrc) * CCH + c0k + lcol);
                } else {
                    half8 z; for (int i = 0; i < 8; ++i) z[i] = (_Float16)0.f; bv[sg] = z;
                }
            }
        }
        // ---- MFMA ----
#pragma unroll
        for (int ks = 0; ks < 2; ++ks) {
            const int ko = ks * 32 + quad * 8;
            half8 af[4], bf[2];
#pragma unroll
            for (int mi = 0; mi < 4; ++mi) af[mi] = *(half8*)(&As[(wm + mi * 16 + l15) * 72 + ko]);
#pragma unroll
            for (int ni = 0; ni < 2; ++ni) bf[ni] = *(half8*)(&Bs[(wn + ni * 16 + l15) * 72 + ko]);
#pragma unroll
            for (int mi = 0; mi < 4; ++mi)
#pragma unroll
                for (int ni = 0; ni < 2; ++ni)
                    acc[mi][ni] = __builtin_amdgcn_mfma_f32_16x16x32_f16(af[mi], bf[ni], acc[mi][ni], 0, 0, 0);
        }
        __syncthreads();
    }

    const float sc = 0.05103103630798288f;  // 1/sqrt(384)
#pragma unroll
    for (int mi = 0; mi < 4; ++mi)
#pragma unroll
        for (int ni = 0; ni < 2; ++ni) {
            const int ccb = wm + mi * 16 + quad * 4;
            const int lp  = wn + ni * 16 + l15;     // p_local in [0,64)
            const int pp  = pt0 + lp;
#pragma unroll
            for (int r2 = 0; r2 < 4; ++r2) {
                const int c2 = ccb + r2;            // o = c2 & 3 == r2 (wave-uniform)
                const size_t oidx = ((size_t)n * CCH + c2) * HWP + pp;
                const float t9 = t8tile[r2 * 64 + lp] * (float)xh[oidx];
                out[oidx] = acc[mi][ni][r2] * sc + t9;
            }
        }
}

extern "C" void kernel_launch(void* const* d_in, const int* in_sizes, int n_in,
                              void* d_out, int out_size, void* d_ws, size_t ws_size,
                              hipStream_t stream) {
    const float* x      = (const float*)d_in[0];
    const float* p2w    = (const float*)d_in[1];
    const float* p5w    = (const float*)d_in[2];
    const float* conv_w = (const float*)d_in[3];
    float* out = (float*)d_out;

    // ws: xh 25.69MB | p2wh 2.41MB | (hole, ex-t8) | t7T 3.15MB | xT 25.69MB
    char* ws = (char*)d_ws;
    _Float16* xh   = (_Float16*)ws;
    _Float16* p2wh = (_Float16*)(ws + 25690112);
    _Float16* t7T  = (_Float16*)(ws + 25690112 + 2408448 + 1605632);
    _Float16* xT   = (_Float16*)(ws + 25690112 + 2408448 + 1605632 + 3145728);
    _Float16* part = (_Float16*)out;  // f16 partials (25.2MB) consumed by reduce before gemm2 writes out

    cvtp2w_kernel<<<dim3(K3C), dim3(256), 0, stream>>>(p2w, p2wh);
    cvt_xt_kernel<<<dim3(3136), dim3(256), 0, stream>>>(x, xh, xT);
    gemm1_kernel<<<dim3(768), dim3(256), 0, stream>>>(xh, p2wh, part);
    reduce_kernel<<<dim3(24, NB), dim3(256), 0, stream>>>(part, t7T);
    gemm2_kernel<<<dim3(1568), dim3(256), 0, stream>>>(xh, xT, t7T, conv_w, p5w, out);
}